// Round 7
// baseline (164.476 us; speedup 1.0000x reference)
//
#include <hip/hip_runtime.h>

// VQ-VAE vector quantizer, MI355X gfx950 — round 11: occupancy fix.
//  r5-r10 invariant: 1-2 blocks/CU, grid <= 2x CUs, every pipe <15% busy,
//  duration ~60-90 µs regardless of which pipe is off-loaded => serial-phase
//  exposure at 2 waves/SIMD, not any single pipe, is the floor.
//  Fix: split into score + gather kernels and code-partition the score:
//   K2a score : 1024 blocks (512 row-groups x 2 code-halves), 256 thr,
//               35.8 KB LDS -> 4 blocks/CU resident, ~16 waves/CU.
//               r5-proven loop (bf16 z-stage, depth-3 GLL ring, counted
//               vmcnt, granule-XOR swizzle). Writes per-row (best,idx)
//               partials; ||z||^2 atomic-added by half 0 only.
//   K2b gather: 512 blocks, merge partials (tie -> lower index), loss sum,
//               rotated DMA-gather of W rows, transposed z_q write, finalize.
//  Distances/tie-breaks bit-identical to r5/r9 -> absmax unchanged.

#define DIM      256
#define NCODES   1024
#define SPB      1024
#define ZQ_ELEMS 8388608
#define NROWS    32768
#define NBLK_A   1024      // 512 row-groups x 2 halves
#define NBLK_B   512

typedef float f32x4  __attribute__((ext_vector_type(4)));
typedef short bf16x8 __attribute__((ext_vector_type(8)));
typedef short bf16x4 __attribute__((ext_vector_type(4)));

__device__ __forceinline__ short f2bf(float f) {
    union { float f; unsigned u; } v; v.f = f;
    unsigned r = v.u + 0x7FFFu + ((v.u >> 16) & 1u);   // RNE
    return (short)(r >> 16);
}

#define GLL16(g, l)                                                            \
    __builtin_amdgcn_global_load_lds(                                          \
        (const __attribute__((address_space(1))) void*)(g),                    \
        (__attribute__((address_space(3))) void*)(l), 16, 0, 0)

#define WAITV(n)  asm volatile("s_waitcnt vmcnt(" #n ")" ::: "memory")
#define WAITLGKM0 asm volatile("s_waitcnt lgkmcnt(0)" ::: "memory")

// ---------------- K1: prep ----------------
__global__ __launch_bounds__(256) void prep(const float* __restrict__ w,
                                            short* __restrict__ wbf,
                                            float* __restrict__ wn,
                                            float* __restrict__ acc,
                                            unsigned* __restrict__ done) {
    const int t = threadIdx.x, wv = t >> 6, l = t & 63;
    const int k = blockIdx.x * 4 + wv;          // one wave per code
    const float* wr = w + (size_t)k * DIM + 4 * l;
    f32x4 v = *(const f32x4*)wr;
    bf16x4 p;
    p[0] = f2bf(v[0]); p[1] = f2bf(v[1]); p[2] = f2bf(v[2]); p[3] = f2bf(v[3]);
    *(bf16x4*)(wbf + (size_t)k * DIM + 4 * l) = p;
    float s = v[0]*v[0] + v[1]*v[1] + v[2]*v[2] + v[3]*v[3];
#pragma unroll
    for (int off = 32; off; off >>= 1) s += __shfl_down(s, off);
    if (l == 0) wn[k] = s;
    if (blockIdx.x == 0 && t == 0) { *acc = 0.f; *done = 0u; }
}

// ---------------- K2a: score (64 rows x 512 codes per block) ----------------
// LDS: smem union: zs bf16 [256 d][66 s] (33792 B, phases 1-2)
//                  B ring 4 tiles x 8192 B (32768 B, phase 3)
// + wnl f32[512].  Total ~35.8 KB -> 4 blocks/CU.
__global__ __launch_bounds__(256)
__attribute__((amdgpu_waves_per_eu(4, 4)))
void vq_score(const float* __restrict__ z,
              const short* __restrict__ wbf,
              const float* __restrict__ wn,
              float* __restrict__ pb,
              int* __restrict__ pi,
              float* __restrict__ acc) {
    __shared__ __align__(16) char smem[33792];
    __shared__ __align__(16) float wnl[512];

    short* zs = (short*)smem;      // [256 d][stride 66] bf16

    const int t   = threadIdx.x;   // 0..255
    const int wv  = t >> 6;        // 0..3
    const int l   = t & 63;
    const int n16 = l & 15;
    const int q   = l >> 4;

    const int rb = blockIdx.x >> 1;        // row-group 0..511
    const int hf = blockIdx.x & 1;         // codebook half
    const int kb = hf << 9;                // code base (0 or 512)

    const int n0    = rb * 64;
    const int batch = n0 >> 10;
    const int sbase = n0 & 1023;
    const float* zb = z + (size_t)batch * DIM * SPB + sbase;

    // ---- phase 1: z -> LDS bf16 [d][s] (stride 66) + sum(z^2); wn-half -> LDS
    {
        const int sx = t & 15;         // f32x4 seg: s = 4sx..4sx+3
        const int cg = t >> 4;         // 16 channel groups
        float lsq = 0.f;
#pragma unroll
        for (int ci = 0; ci < 16; ++ci) {
            const int c = cg + 16 * ci;
            f32x4 v = *(const f32x4*)(zb + (size_t)c * SPB + 4 * sx);
            bf16x4 p;
            p[0] = f2bf(v[0]); p[1] = f2bf(v[1]);
            p[2] = f2bf(v[2]); p[3] = f2bf(v[3]);
            *(bf16x4*)&zs[66 * c + 4 * sx] = p;
            lsq += v[0]*v[0] + v[1]*v[1] + v[2]*v[2] + v[3]*v[3];
        }
#pragma unroll
        for (int off = 32; off; off >>= 1) lsq += __shfl_down(lsq, off);
        if (hf == 0 && l == 0) atomicAdd(acc, lsq);   // count z^2 once
    }
    if (t < 128) *(f32x4*)&wnl[4 * t] = *(const f32x4*)(wn + kb + 4 * t);
    __syncthreads();

    // ---- phase 2: A fragments; wave wv owns rows 16wv..16wv+15
    // lane (q,n16): row = 16wv+n16, dims d = 32T+8q+j (bank-verified free)
    bf16x8 af[8];
#pragma unroll
    for (int T = 0; T < 8; ++T) {
        bf16x8 a;
#pragma unroll
        for (int j = 0; j < 8; ++j)
            a[j] = zs[66 * (32 * T + 8 * q + j) + 16 * wv + n16];
        af[T] = a;
    }
    __syncthreads();               // zs dead; B ring region free

    // ---- phase 3: depth-3 DMA ring, 32 tiles x 16 codes, 4 x 8 KB buffers
    char* bb = smem;
    const short* wq = wbf + ((size_t)kb << 8);   // kb * DIM shorts
    int soff[2];                   // staging src granule-XOR swizzle
#pragma unroll
    for (int i = 0; i < 2; ++i) {
        const int G = i * 256 + t;           // tile granule 0..511
        const int n = G >> 5, p = G & 31;    // code-in-tile, phys granule
        soff[i] = n * 256 + 8 * (p ^ (n & 7));
    }
    int offT[8];                   // frag read: code n16, granule (4T+q)^
#pragma unroll
    for (int T = 0; T < 8; ++T)
        offT[T] = n16 * 512 + ((4 * T + q) ^ (n16 & 7)) * 16;

#pragma unroll
    for (int pt = 0; pt < 3; ++pt) {
        const short* gb = wq + (size_t)pt * 4096;
        char* db = bb + pt * 8192;
#pragma unroll
        for (int i = 0; i < 2; ++i)
            GLL16(gb + soff[i], db + (i * 256 + t) * 16);
    }

    float best[4];
    int   bidx[4];
#pragma unroll
    for (int r = 0; r < 4; ++r) { best[r] = 3.4e38f; bidx[r] = 0; }

    for (int kt = 0; kt < 32; ++kt) {
        if (kt <= 28) {
            const short* gb = wq + (size_t)(kt + 3) * 4096;
            char* db = bb + ((kt + 3) & 3) * 8192;
#pragma unroll
            for (int i = 0; i < 2; ++i)
                GLL16(gb + soff[i], db + (i * 256 + t) * 16);
            WAITV(6);              // tile kt landed; kt+1..kt+3 in flight
        } else if (kt == 29) { WAITV(4); }
        else if (kt == 30)   { WAITV(2); }
        else                 { WAITV(0); }
        __builtin_amdgcn_s_barrier();

        const float wk = wnl[16 * kt + n16];
        const int   k  = kb + 16 * kt + n16;

        const char* wp = bb + (kt & 3) * 8192;
        f32x4 a0 = {0.f, 0.f, 0.f, 0.f};
        __builtin_amdgcn_s_setprio(1);
#pragma unroll
        for (int T = 0; T < 8; ++T) {
            bf16x8 b = *(const bf16x8*)(wp + offT[T]);
            a0 = __builtin_amdgcn_mfma_f32_16x16x32_bf16(af[T], b, a0, 0, 0, 0);
        }
        __builtin_amdgcn_s_setprio(0);
#pragma unroll
        for (int r = 0; r < 4; ++r) {
            float d0 = wk - 2.f * a0[r];
            if (d0 < best[r]) { best[r] = d0; bidx[r] = k; }
        }
        WAITLGKM0;                 // all ds_reads of this buf retired
        __builtin_amdgcn_s_barrier();
    }

    // ---- phase 4: per-wave argmin over 16 code lanes; write partials
    // row (within group) = 16wv + 4q + r
#pragma unroll
    for (int r = 0; r < 4; ++r) {
        float bv = best[r];
        int   bi = bidx[r];
#pragma unroll
        for (int m = 1; m < 16; m <<= 1) {
            float ov = __shfl_xor(bv, m);
            int   oi = __shfl_xor(bi, m);
            if (ov < bv || (ov == bv && oi < bi)) { bv = ov; bi = oi; }
        }
        if (n16 == 0) {
            const int g = hf * NROWS + n0 + 16 * wv + 4 * q + r;
            pb[g] = bv;
            pi[g] = bi;
        }
    }
}

// ---------------- K2b: merge + gather + z_q write + loss finalize ----------
// LDS: zql fp32 64 rows x 1 KB (65536 B, rotated) + sidx i32[64]
__global__ __launch_bounds__(256)
void vq_gather(const float* __restrict__ w,
               const float* __restrict__ pb,
               const int* __restrict__ pi,
               float* __restrict__ out,
               float* __restrict__ acc,
               unsigned* __restrict__ done) {
    __shared__ __align__(16) char smem[65536];
    __shared__ int sidx[64];

    float* zql = (float*)smem;     // [64 s][256 dwords], s-rotated

    const int t  = threadIdx.x;
    const int wv = t >> 6;
    const int l  = t & 63;

    const int n0    = blockIdx.x * 64;
    const int batch = n0 >> 10;
    const int sbase = n0 & 1023;
    float* ob = out + (size_t)batch * DIM * SPB + sbase;

    // ---- merge partials (tie -> lower index; half0 indices < half1's) + loss
    if (t < 64) {
        float bv = pb[n0 + t];
        int   bi = pi[n0 + t];
        const float ov = pb[NROWS + n0 + t];
        const int   oi = pi[NROWS + n0 + t];
        if (ov < bv || (ov == bv && oi < bi)) { bv = ov; bi = oi; }
        sidx[t] = bi;
        float rs = bv;             // winning distance of this row
#pragma unroll
        for (int off = 32; off; off >>= 1) rs += __shfl_down(rs, off);
        if (t == 0) atomicAdd(acc, rs);
    }
    __syncthreads();

    // ---- DMA-gather 64 selected rows (1 KB each), rotated by (j>>2) granules
    // logical dword c of row j lands at phys dword (c + 4*(j>>2)) & 255
#pragma unroll
    for (int i = 0; i < 16; ++i) {
        const int j  = 16 * wv + i;
        const int ks = sidx[j];
        const float* src = w + ((size_t)ks << 8) + 4 * ((l - (j >> 2)) & 63);
        GLL16(src, (char*)smem + j * 1024 + l * 16);
    }
    WAITV(0);
    __syncthreads();

    // ---- transposed z_q write (bank = cg+4u mod 32: exactly 2-way, free)
    {
        const int u  = t & 7;      // s-quad within 32-row window
        const int cg = t >> 3;     // 32 channel groups
#pragma unroll
        for (int p = 0; p < 2; ++p) {
#pragma unroll
            for (int ci = 0; ci < 8; ++ci) {
                const int c = cg + 32 * ci;
                f32x4 qv;
#pragma unroll
                for (int r = 0; r < 4; ++r)
                    qv[r] = zql[(32 * p + 4 * u + r) * 256 +
                                ((c + 32 * p + 4 * u) & 255)];
                __builtin_nontemporal_store(
                    qv, (f32x4*)(ob + (size_t)c * SPB + 32 * p + 4 * u));
            }
        }
    }

    if (t == 0) {
        __threadfence();
        unsigned prev = atomicAdd(done, 1u);
        if (prev == NBLK_B - 1) {
            float val = atomicAdd(acc, 0.f) * (1.f / 8388608.f);
            out[ZQ_ELEMS]     = val;
            out[ZQ_ELEMS + 1] = val;
        }
    }
}

extern "C" void kernel_launch(void* const* d_in, const int* in_sizes, int n_in,
                              void* d_out, int out_size, void* d_ws, size_t ws_size,
                              hipStream_t stream) {
    const float* z = (const float*)d_in[0];
    const float* w = (const float*)d_in[1];
    float* out = (float*)d_out;

    char* ws = (char*)d_ws;
    short*    wbf  = (short*)ws;                   // 512 KB
    float*    wn   = (float*)(ws + 524288);        // 4 KB
    float*    acc  = (float*)(ws + 528384);
    unsigned* done = (unsigned*)(ws + 528388);
    float*    pb   = (float*)(ws + 532480);        // 256 KB (2 x 32768 f32)
    int*      pi   = (int*)  (ws + 794624);        // 256 KB (2 x 32768 i32)

    prep<<<256, 256, 0, stream>>>(w, wbf, wn, acc, done);
    vq_score<<<NBLK_A, 256, 0, stream>>>(z, wbf, wn, pb, pi, acc);
    vq_gather<<<NBLK_B, 256, 0, stream>>>(w, pb, pi, out, acc, done);
}